// Round 19
// baseline (609.188 us; speedup 1.0000x reference)
//
#include <hip/hip_runtime.h>

constexpr int B_ = 8;
constexpr int N_ = 2048;
constexpr int K_ = 20;
constexpr float SLOPE_ = 0.2f;

typedef __attribute__((ext_vector_type(8))) short bf16x8;
typedef __attribute__((ext_vector_type(4))) float f32x4;

__device__ __forceinline__ float lrelu(float v) { return v > 0.0f ? v : SLOPE_ * v; }

__device__ __forceinline__ void async16(const void* g, void* l) {
  __builtin_amdgcn_global_load_lds((const __attribute__((address_space(1))) unsigned int*)g,
                                   (__attribute__((address_space(3))) unsigned int*)l, 16, 0, 0);
}

__device__ __forceinline__ unsigned long long shflx64(unsigned long long v, int m) {
  return __shfl_xor(v, m, 64);
}

__device__ __forceinline__ unsigned short f2bf(float f) {
  unsigned u = __float_as_uint(f);
  u += 0x7fff + ((u >> 16) & 1);
  return (unsigned short)(u >> 16);
}

// Build Wp[2O x C]: rows [0,O) = Wd = W[:, :C]; rows [O,2O) = Wc - Wd
__global__ void prep_wp(const float* __restrict__ W, float* __restrict__ Wp, int O, int C) {
  int i = blockIdx.x * 256 + threadIdx.x;
  if (i >= 2 * O * C) return;
  int o = i / C, c = i - o * C;
  if (o < O)
    Wp[i] = W[o * 2 * C + c];
  else
    Wp[i] = W[(o - O) * 2 * C + C + c] - W[(o - O) * 2 * C + c];
}

// fp32 -> bf16 (RNE), vectorized x4, contiguous
__global__ void cvt_bf16(const float4* __restrict__ src, ushort4* __restrict__ dst, int n4) {
  int i = blockIdx.x * 256 + threadIdx.x;
  if (i >= n4) return;
  float4 v = src[i];
  ushort4 o = {f2bf(v.x), f2bf(v.y), f2bf(v.z), f2bf(v.w)};
  dst[i] = o;
}

// hcat[:,128:256) fp32 -> bf16 interleaved at hcat ushort-offset row*1024+512
__global__ void cvt_rows_bf16(float* __restrict__ hcat) {
  int i = blockIdx.x * 256 + threadIdx.x;
  if (i >= B_ * N_ * 32) return;
  int row = i >> 5, seg = i & 31;
  float4 v = *(const float4*)(hcat + (size_t)row * 512 + 128 + seg * 4);
  ushort4 o = {f2bf(v.x), f2bf(v.y), f2bf(v.z), f2bf(v.w)};
  *(ushort4*)((unsigned short*)hcat + (size_t)row * 1024 + 512 + seg * 4) = o;
}

// norms of x rows (C=3)
__global__ void norms_x(const float* __restrict__ x, float* __restrict__ xx) {
  int i = blockIdx.x * 256 + threadIdx.x;
  if (i >= B_ * N_) return;
  const float* p = x + (size_t)i * 3;
  xx[i] = p[0] * p[0] + p[1] * p[1] + p[2] * p[2];
}

// Transpose features: hin rows (stride, C cols) -> xT[b][CP][N_], zero-padded.
template <int C, int CP>
__global__ __launch_bounds__(256) void transpose_feat(const float* __restrict__ hin, int stride,
                                                      float* __restrict__ xT) {
  __shared__ float ts[64][CP + 1];
  const int b = blockIdx.x & 7, n0 = (blockIdx.x >> 3) * 64;  // XCD-pinned batch
  for (int i = threadIdx.x; i < 64 * C; i += 256) {
    int n = i / C, c = i - n * C;
    ts[n][c] = hin[(size_t)(b * N_ + n0 + n) * stride + c];
  }
  if (CP > C)
    for (int i = threadIdx.x; i < 64 * (CP - C); i += 256) {
      int n = i / (CP - C), c = C + (i - n * (CP - C));
      ts[n][c] = 0.0f;
    }
  __syncthreads();
  for (int i = threadIdx.x; i < 64 * CP; i += 256) {
    int c = i >> 6, n = i & 63;
    xT[((size_t)b * CP + c) * N_ + n0 + n] = ts[n][c];
  }
}

// kNN v12b (m-split, ownership FIXED): 16 queries/block over HALF the candidate
// range (1024); per-block xT traffic halves vs R9 at identical per-thread FMA and
// identical block count (2048) — A/B test of L2 bandwidth contention. 256 threads
// = 4 waves; selection runs 4 ROUNDS of 4 queries (R18's crash: 8-query rounds
// with only 4 waves left half the queries unselected -> poison indices).
// acc[16][4] = 64 regs (no-spill boundary). Thread owns m = h*1024 + tid*4 + j.
// Exchange per round: d2s[4][1024] (16 KB); wave w owns query r*4+w with the
// half's 1024 candidates in r2[16] (global m = h*1024 + i*64 + lane).
// Selection: threshold (20th-smallest lane-min) + ballot-compact + u64 bitonic
// sort (exact-pop fallback if cnt > 64); 20 best (d2bits<<32|m) -> hb[q][h][20].
template <int C, int CP>
__global__ __launch_bounds__(256) void knn_kernel(const float* __restrict__ hin, int stride,
                                                  const float* __restrict__ xT,
                                                  const float* __restrict__ xx,
                                                  unsigned long long* __restrict__ hb) {
  const int b = blockIdx.x & 7;          // XCD-pinned batch
  const int rest = blockIdx.x >> 3;
  const int h = rest & 1;                // m-half
  const int q0 = (rest >> 1) * 16;       // 16-query tile
  const int tid = threadIdx.x;
  const int w = tid >> 6, lane = tid & 63;
  const int bN = b * N_;

  __shared__ float d2s[4][1024];              // exchange buffer (16 KB)
  __shared__ unsigned long long cbuf[4][64];  // per-wave compact buffers (2 KB)

  const float* qrow0 = hin + (size_t)(bN + q0) * stride;  // wave-uniform -> s_load

  float acc[16][4] = {};  // [q][j], m = h*1024 + tid*4 + j
  const float* xcol = xT + (size_t)b * CP * N_ + h * 1024 + tid * 4;

#pragma unroll 4
  for (int c = 0; c < CP; c++) {
    float4 x0 = *(const float4*)(xcol + (size_t)c * N_);
    float xv[4] = {x0.x, x0.y, x0.z, x0.w};
#pragma unroll
    for (int q = 0; q < 16; q++) {
      float qv;
      if constexpr (CP == C)
        qv = qrow0[(size_t)q * stride + c];
      else
        qv = (c < C) ? qrow0[(size_t)q * stride + c] : 0.0f;
#pragma unroll
      for (int j = 0; j < 4; j++) acc[q][j] = fmaf(xv[j], qv, acc[q][j]);
    }
  }

  // d2 = max(xx_m + xx_q - 2*dot, 0)
  float4 xm = *(const float4*)(xx + bN + h * 1024 + tid * 4);
  float xxm[4] = {xm.x, xm.y, xm.z, xm.w};
#pragma unroll
  for (int q = 0; q < 16; q++) {
    float qn = xx[bN + q0 + q];  // uniform -> s_load
#pragma unroll
    for (int j = 0; j < 4; j++)
      acc[q][j] = fmaxf(fmaf(-2.0f, acc[q][j], xxm[j] + qn), 0.0f);
  }

  const float INF = __int_as_float(0x7f800000);
  const int mglob = h * 1024;  // global m offset of this half

#pragma unroll
  for (int r = 0; r < 4; r++) {
    __syncthreads();  // previous round's r2 reads complete
#pragma unroll
    for (int qq = 0; qq < 4; qq++) {
      const int q = r * 4 + qq;
      float4 v = {acc[q][0], acc[q][1], acc[q][2], acc[q][3]};
      *(float4*)&d2s[qq][tid * 4] = v;
    }
    __syncthreads();
    // wave w owns query r*4+w; r2[i] = d2 of local m = i*64 + lane
    float r2[16];
#pragma unroll
    for (int i = 0; i < 16; i++) r2[i] = d2s[w][i * 64 + lane];

    unsigned long long* cb = cbuf[w];
    unsigned long long* outp = hb + ((size_t)(bN + q0 + r * 4 + w) * 2 + h) * K_;

    // ---- threshold: T = 20th-smallest per-lane min ----
    float lmin = r2[0];
#pragma unroll
    for (int i = 1; i < 16; i++) lmin = fminf(lmin, r2[i]);
    float sv = lmin;
#pragma unroll
    for (int k = 2; k <= 64; k <<= 1)
#pragma unroll
      for (int j = k >> 1; j > 0; j >>= 1) {
        float p = __shfl_xor(sv, j, 64);
        bool takeMax = ((lane & j) != 0) == ((lane & k) == 0);
        sv = takeMax ? fmaxf(sv, p) : fminf(sv, p);
      }
    float T = __shfl(sv, 19, 64);

    // ---- count + compact candidates <= T ----
    unsigned cnt = 0;
#pragma unroll
    for (int i = 0; i < 16; i++) {
      bool pred = r2[i] <= T;
      unsigned long long mk = __ballot(pred);
      if (mk) {
        int off = __popcll(mk & ((1ull << lane) - 1ull));
        unsigned pos = cnt + (unsigned)off;
        if (pred && pos < 64)
          cb[pos] = ((unsigned long long)__float_as_uint(r2[i]) << 32) |
                    (unsigned)(mglob + i * 64 + lane);
        cnt += (unsigned)__popcll(mk);
      }
    }

    if (cnt <= 64) {
      unsigned long long v = (lane < (int)cnt) ? cb[lane] : ~0ull;
#pragma unroll
      for (int k = 2; k <= 64; k <<= 1)
#pragma unroll
        for (int j = k >> 1; j > 0; j >>= 1) {
          unsigned long long p = shflx64(v, j);
          bool takeMax = ((lane & j) != 0) == ((lane & k) == 0);
          bool lt = v < p;
          v = (takeMax == lt) ? p : v;
        }
      if (lane < K_) outp[lane] = v;
    } else {
      for (int t2 = 0; t2 < K_; t2++) {
        unsigned long long loc = ~0ull;
#pragma unroll
        for (int i = 0; i < 16; i++) {
          unsigned long long u = ((unsigned long long)__float_as_uint(r2[i]) << 32) |
                                 (unsigned)(mglob + i * 64 + lane);
          loc = u < loc ? u : loc;
        }
#pragma unroll
        for (int off = 32; off > 0; off >>= 1) {
          unsigned long long vv = shflx64(loc, off);
          loc = vv < loc ? vv : loc;
        }
        if (lane == 0) cb[t2] = loc;
        const int mwin = (int)(unsigned)(loc & 0xffffffffull) - mglob;
#pragma unroll
        for (int i = 0; i < 16; i++)
          if (i * 64 + lane == mwin) r2[i] = INF;
      }
      if (lane < K_) outp[lane] = cb[lane];
    }
  }
}

// Exact merge of the two per-half top-20 lists: one wave per query; 40 u64
// candidates (global top-20 is a subset of the union) -> bitonic-64 -> 20 best.
__global__ __launch_bounds__(256) void knn_merge(const unsigned long long* __restrict__ hb,
                                                 int* __restrict__ idxo) {
  const int q = blockIdx.x * 4 + (threadIdx.x >> 6);
  const int lane = threadIdx.x & 63;
  unsigned long long v = (lane < 2 * K_) ? hb[(size_t)q * 2 * K_ + lane] : ~0ull;
#pragma unroll
  for (int k = 2; k <= 64; k <<= 1)
#pragma unroll
    for (int j = k >> 1; j > 0; j >>= 1) {
      unsigned long long p = shflx64(v, j);
      bool takeMax = ((lane & j) != 0) == ((lane & k) == 0);
      bool lt = v < p;
      v = (takeMax == lt) ? p : v;
    }
  if (lane < K_) idxo[(size_t)q * K_ + lane] = (int)(unsigned)(v & 0xffffffffull);
}

// P[row, o'] = sum_c h[row, c] * Wp[o', c]; XCD-pinned row tiles.
template <int C, int O2>
__global__ void proj_kernel(const float* __restrict__ hin, int stride,
                            const float* __restrict__ Wp, float* __restrict__ P) {
  const int nt = (blockIdx.x & 7) * N_ + (blockIdx.x >> 3) * 16;  // XCD-pinned
  const int o = blockIdx.y * blockDim.x + threadIdx.x;
  __shared__ float hs[16][C];
  for (int i = threadIdx.x; i < 16 * C; i += blockDim.x) {
    int r = i / C, c = i - r * C;
    hs[r][c] = hin[(size_t)(nt + r) * stride + c];
  }
  __syncthreads();
  float acc[16];
#pragma unroll
  for (int t = 0; t < 16; t++) acc[t] = 0.0f;
  const float* wr = Wp + (size_t)o * C;
  if constexpr (C % 4 == 0) {
    for (int cg = 0; cg < C; cg += 4) {
      float4 w = *(const float4*)(wr + cg);
#pragma unroll
      for (int t = 0; t < 16; t++) {
        float4 h = *(const float4*)(&hs[t][cg]);
        acc[t] += w.x * h.x + w.y * h.y + w.z * h.z + w.w * h.w;
      }
    }
  } else {
    for (int c = 0; c < C; c++) {
      float w = wr[c];
#pragma unroll
      for (int t = 0; t < 16; t++) acc[t] += w * hs[t][c];
    }
  }
#pragma unroll
  for (int t = 0; t < 16; t++) P[(size_t)(nt + t) * O2 + o] = acc[t];
}

// Layer-4 proj via bf16 MFMA (K=128), XCD-pinned m-tiles.
__global__ __launch_bounds__(256) void gemm_proj(const unsigned short* __restrict__ A, int astride,
                                                 const unsigned short* __restrict__ Bw,
                                                 float* __restrict__ P) {
  const int m0 = ((blockIdx.x & 7) * 16 + (blockIdx.x >> 3)) * 128;  // XCD-pinned
  const int n0 = blockIdx.y * 128;
  const int tid = threadIdx.x;
  const int w = tid >> 6, lane = tid & 63;
  const int wm = w & 1, wn = w >> 1;

  __shared__ unsigned short lA[128 * 32];
  __shared__ unsigned short lB[128 * 32];

  const int r0 = (w * 2 + 0) * 16 + (lane >> 2);
  const int r1 = (w * 2 + 1) * 16 + (lane >> 2);
  const int ks = (lane & 3) * 8;
  const unsigned short* a0 = A + (size_t)(m0 + r0) * astride + ks;
  const unsigned short* a1 = A + (size_t)(m0 + r1) * astride + ks;
  const unsigned short* b0 = Bw + (size_t)(n0 + r0) * 128 + ks;
  const unsigned short* b1 = Bw + (size_t)(n0 + r1) * 128 + ks;
  unsigned short* lA0 = lA + (w * 2 + 0) * 512;
  unsigned short* lA1 = lA + (w * 2 + 1) * 512;
  unsigned short* lB0 = lB + (w * 2 + 0) * 512;
  unsigned short* lB1 = lB + (w * 2 + 1) * 512;

  f32x4 acc[4][4] = {};
  const int ka = (lane >> 4) * 8;

  for (int k0 = 0; k0 < 128; k0 += 32) {
    __syncthreads();
    async16(a0 + k0, lA0);
    async16(a1 + k0, lA1);
    async16(b0 + k0, lB0);
    async16(b1 + k0, lB1);
    __syncthreads();
    bf16x8 af[4], bfr[4];
#pragma unroll
    for (int mt = 0; mt < 4; mt++)
      af[mt] = *(const bf16x8*)&lA[(wm * 64 + mt * 16 + (lane & 15)) * 32 + ka];
#pragma unroll
    for (int nt = 0; nt < 4; nt++)
      bfr[nt] = *(const bf16x8*)&lB[(wn * 64 + nt * 16 + (lane & 15)) * 32 + ka];
#pragma unroll
    for (int mt = 0; mt < 4; mt++)
#pragma unroll
      for (int nt = 0; nt < 4; nt++)
        acc[mt][nt] = __builtin_amdgcn_mfma_f32_16x16x32_bf16(af[mt], bfr[nt], acc[mt][nt], 0, 0, 0);
  }

  const int col = n0 + wn * 64 + (lane & 15);
  const int rowb = m0 + wm * 64 + (lane >> 4) * 4;
#pragma unroll
  for (int mt = 0; mt < 4; mt++)
#pragma unroll
    for (int nt = 0; nt < 4; nt++)
#pragma unroll
      for (int r = 0; r < 4; r++)
        P[(size_t)(rowb + mt * 16 + r) * 512 + col + nt * 16] = acc[mt][nt][r];
}

// Combine: 256 threads handle ROWS=256/O rows; XCD-pinned.
template <int O>
__global__ __launch_bounds__(256) void combine_kernel(const float* __restrict__ P,
                                                      const int* __restrict__ idxo,
                                                      const float* __restrict__ bias,
                                                      float* __restrict__ hout,
                                                      float* __restrict__ xxo) {
  constexpr int ROWS = 256 / O;
  const int bb = blockIdx.x & 7;
  const int rt = blockIdx.x >> 3;
  const int r = threadIdx.x / O;
  const int o = threadIdx.x & (O - 1);
  const int row = bb * N_ + rt * ROWS + r;
  __shared__ int idxs[ROWS][K_];
  __shared__ float ps[ROWS][O / 64 > 0 ? O / 64 : 1];
  if (o < K_) idxs[r][o] = idxo[(size_t)row * K_ + o];
  __syncthreads();
  const int base_row = bb * N_;
  float g = -3.4e38f;
#pragma unroll
  for (int k = 0; k < K_; k++) {
    float v = P[(size_t)(base_row + idxs[r][k]) * (2 * O) + o];
    g = fmaxf(g, v);
  }
  float ba = P[(size_t)row * (2 * O) + O + o];
  float val = lrelu(g + ba + bias[o]);
  hout[(size_t)row * 512 + o] = val;
  if (xxo) {
    float sq = val * val;
#pragma unroll
    for (int off = 32; off > 0; off >>= 1) sq += __shfl_xor(sq, off, 64);
    if constexpr (O == 64) {
      if (o == 0) xxo[row] = sq;
    } else {
      if ((threadIdx.x & 63) == 0) ps[r][o >> 6] = sq;
      __syncthreads();
      if (o == 0) {
        float t = ps[r][0];
#pragma unroll
        for (int u = 1; u < O / 64; u++) t += ps[r][u];
        xxo[row] = t;
      }
    }
  }
}

// Final GEMM: 128x128 tile, BK=32, bf16 MFMA, max-over-rows epilogue; XCD-pinned.
__global__ __launch_bounds__(256) void gemm_final(const unsigned short* __restrict__ A,
                                                  const unsigned short* __restrict__ Bw,
                                                  float* __restrict__ part) {
  const int mt5 = (blockIdx.x & 7) * 16 + (blockIdx.x >> 3);
  const int m0 = mt5 * 128;
  const int n0 = blockIdx.y * 128;
  const int tid = threadIdx.x;
  const int w = tid >> 6, lane = tid & 63;
  const int wm = w & 1, wn = w >> 1;

  __shared__ unsigned short lA[128 * 32];
  __shared__ unsigned short lB[128 * 32];
  __shared__ float ldsred[2][128];

  const int r0 = (w * 2 + 0) * 16 + (lane >> 2);
  const int r1 = (w * 2 + 1) * 16 + (lane >> 2);
  const int ks = (lane & 3) * 8;
  const unsigned short* a0 = A + (size_t)(m0 + r0) * 512 + ks;
  const unsigned short* a1 = A + (size_t)(m0 + r1) * 512 + ks;
  const unsigned short* b0 = Bw + (size_t)(n0 + r0) * 512 + ks;
  const unsigned short* b1 = Bw + (size_t)(n0 + r1) * 512 + ks;
  unsigned short* lA0 = lA + (w * 2 + 0) * 512;
  unsigned short* lA1 = lA + (w * 2 + 1) * 512;
  unsigned short* lB0 = lB + (w * 2 + 0) * 512;
  unsigned short* lB1 = lB + (w * 2 + 1) * 512;

  f32x4 acc[4][4] = {};
  const int ka = (lane >> 4) * 8;

  for (int k0 = 0; k0 < 512; k0 += 32) {
    __syncthreads();
    async16(a0 + k0, lA0);
    async16(a1 + k0, lA1);
    async16(b0 + k0, lB0);
    async16(b1 + k0, lB1);
    __syncthreads();
    bf16x8 af[4], bfr[4];
#pragma unroll
    for (int mt = 0; mt < 4; mt++)
      af[mt] = *(const bf16x8*)&lA[(wm * 64 + mt * 16 + (lane & 15)) * 32 + ka];
#pragma unroll
    for (int nt = 0; nt < 4; nt++)
      bfr[nt] = *(const bf16x8*)&lB[(wn * 64 + nt * 16 + (lane & 15)) * 32 + ka];
#pragma unroll
    for (int mt = 0; mt < 4; mt++)
#pragma unroll
      for (int nt = 0; nt < 4; nt++)
        acc[mt][nt] = __builtin_amdgcn_mfma_f32_16x16x32_bf16(af[mt], bfr[nt], acc[mt][nt], 0, 0, 0);
  }

#pragma unroll
  for (int nt = 0; nt < 4; nt++) {
    float v = -3.4e38f;
#pragma unroll
    for (int mt = 0; mt < 4; mt++)
#pragma unroll
      for (int r = 0; r < 4; r++) v = fmaxf(v, acc[mt][nt][r]);
    v = fmaxf(v, __shfl_xor(v, 16, 64));
    v = fmaxf(v, __shfl_xor(v, 32, 64));
    if (lane < 16) ldsred[wm][wn * 64 + nt * 16 + lane] = v;
  }
  __syncthreads();
  if (tid < 128) {
    float v = fmaxf(ldsred[0][tid], ldsred[1][tid]);
    const int b = blockIdx.x & 7, s5 = blockIdx.x >> 3;
    part[(size_t)(b * 16 + s5) * 1024 + n0 + tid] = v;
  }
}

__global__ void final_reduce(const float* __restrict__ part, const float* __restrict__ bf,
                             float* __restrict__ out) {
  int i = blockIdx.x * 256 + threadIdx.x;
  if (i >= B_ * 1024) return;
  int b = i >> 10, o = i & 1023;
  float m = -3.4e38f;
  for (int s = 0; s < 16; s++) m = fmaxf(m, part[(size_t)(b * 16 + s) * 1024 + o]);
  out[i] = lrelu(m + bf[o]);
}

extern "C" void kernel_launch(void* const* d_in, const int* in_sizes, int n_in, void* d_out,
                              int out_size, void* d_ws, size_t ws_size, hipStream_t stream) {
  (void)in_sizes; (void)n_in; (void)out_size; (void)ws_size;
  const float* x = (const float*)d_in[0];
  const float* W1 = (const float*)d_in[1];
  const float* b1 = (const float*)d_in[2];
  const float* W2 = (const float*)d_in[3];
  const float* b2 = (const float*)d_in[4];
  const float* W3 = (const float*)d_in[5];
  const float* b3 = (const float*)d_in[6];
  const float* W4 = (const float*)d_in[7];
  const float* b4 = (const float*)d_in[8];
  const float* Wf = (const float*)d_in[9];
  const float* bf = (const float*)d_in[10];

  float* ws = (float*)d_ws;
  float* hcat = ws;                               // B*N*512 floats (32 MB)
  float* P = hcat + (size_t)B_ * N_ * 512;        // B*N*512 floats (32 MB)
  int* idx = (int*)(P + (size_t)B_ * N_ * 512);   // B*N*20 ints
  float* Wp = (float*)(idx + (size_t)B_ * N_ * K_);
  float* part = Wp + 512 * 128;                   // 8*16*1024 floats
  float* xxb = part + 8 * 16 * 1024;              // B*N floats (row norms)
  float* out = (float*)d_out;
  float* xT = P;                                  // alias P[0..2M floats): dead before proj
  // per-half top-20 scratch: P offset 4M floats (16 MB) — beyond xT, dead until proj
  unsigned long long* hb = (unsigned long long*)(P + (size_t)4 * 1024 * 1024);
  unsigned short* hcat_bf = (unsigned short*)P;   // alias P (dead after layer-4)
  unsigned short* Wf_bf = hcat_bf + (size_t)B_ * N_ * 512;
  unsigned short* A4_bf = (unsigned short*)hcat + 512;  // interleaved, stride 1024 ushorts
  unsigned short* Wp_bf = (unsigned short*)part;        // part dead until gemm_final

  dim3 knng(N_ / 16 * 2 * B_);  // 2048: b = x&7, h = (x>>3)&1, qtile = x>>4
  dim3 mrg(B_ * N_ / 4);
  dim3 trg(N_ / 64 * B_);

  // Layer 1: C=3 -> O=64
  prep_wp<<<(2 * 64 * 3 + 255) / 256, 256, 0, stream>>>(W1, Wp, 64, 3);
  norms_x<<<(B_ * N_ + 255) / 256, 256, 0, stream>>>(x, xxb);
  transpose_feat<3, 4><<<trg, 256, 0, stream>>>(x, 3, xT);
  knn_kernel<3, 4><<<knng, 256, 0, stream>>>(x, 3, xT, xxb, hb);
  knn_merge<<<mrg, 256, 0, stream>>>(hb, idx);
  proj_kernel<3, 128><<<dim3(B_ * N_ / 16, 1), 128, 0, stream>>>(x, 3, Wp, P);
  combine_kernel<64><<<B_ * N_ / 4, 256, 0, stream>>>(P, idx, b1, hcat + 0, xxb);

  // Layer 2: C=64 -> O=64
  prep_wp<<<(2 * 64 * 64 + 255) / 256, 256, 0, stream>>>(W2, Wp, 64, 64);
  transpose_feat<64, 64><<<trg, 256, 0, stream>>>(hcat + 0, 512, xT);
  knn_kernel<64, 64><<<knng, 256, 0, stream>>>(hcat + 0, 512, xT, xxb, hb);
  knn_merge<<<mrg, 256, 0, stream>>>(hb, idx);
  proj_kernel<64, 128><<<dim3(B_ * N_ / 16, 1), 128, 0, stream>>>(hcat + 0, 512, Wp, P);
  combine_kernel<64><<<B_ * N_ / 4, 256, 0, stream>>>(P, idx, b2, hcat + 64, xxb);

  // Layer 3: C=64 -> O=128
  prep_wp<<<(2 * 128 * 64 + 255) / 256, 256, 0, stream>>>(W3, Wp, 128, 64);
  transpose_feat<64, 64><<<trg, 256, 0, stream>>>(hcat + 64, 512, xT);
  knn_kernel<64, 64><<<knng, 256, 0, stream>>>(hcat + 64, 512, xT, xxb, hb);
  knn_merge<<<mrg, 256, 0, stream>>>(hb, idx);
  proj_kernel<64, 256><<<dim3(B_ * N_ / 16, 1), 256, 0, stream>>>(hcat + 64, 512, Wp, P);
  combine_kernel<128><<<B_ * N_ / 2, 256, 0, stream>>>(P, idx, b3, hcat + 128, xxb);

  // Layer 4: C=128 -> O=256; proj via bf16 MFMA
  prep_wp<<<(2 * 256 * 128 + 255) / 256, 256, 0, stream>>>(W4, Wp, 256, 128);
  transpose_feat<128, 128><<<trg, 256, 0, stream>>>(hcat + 128, 512, xT);
  knn_kernel<128, 128><<<knng, 256, 0, stream>>>(hcat + 128, 512, xT, xxb, hb);
  knn_merge<<<mrg, 256, 0, stream>>>(hb, idx);
  cvt_rows_bf16<<<(B_ * N_ * 32 + 255) / 256, 256, 0, stream>>>(hcat);
  cvt_bf16<<<(512 * 128 / 4 + 255) / 256, 256, 0, stream>>>(
      (const float4*)Wp, (ushort4*)Wp_bf, 512 * 128 / 4);
  gemm_proj<<<dim3(B_ * N_ / 128, 4), 256, 0, stream>>>(A4_bf, 1024, Wp_bf, P);
  combine_kernel<256><<<B_ * N_, 256, 0, stream>>>(P, idx, b4, hcat + 256, nullptr);

  // Final 1x1 conv via bf16 MFMA + fused max-over-rows
  cvt_bf16<<<(B_ * N_ * 512 / 4 + 255) / 256, 256, 0, stream>>>(
      (const float4*)hcat, (ushort4*)hcat_bf, B_ * N_ * 512 / 4);
  cvt_bf16<<<(1024 * 512 / 4 + 255) / 256, 256, 0, stream>>>(
      (const float4*)Wf, (ushort4*)Wf_bf, 1024 * 512 / 4);
  gemm_final<<<dim3(128, 8), 256, 0, stream>>>(hcat_bf, Wf_bf, part);
  final_reduce<<<(B_ * 1024 + 255) / 256, 256, 0, stream>>>(part, bf, out);
}

// Round 20
// 539.954 us; speedup vs baseline: 1.1282x; 1.1282x over previous
//
#include <hip/hip_runtime.h>

constexpr int B_ = 8;
constexpr int N_ = 2048;
constexpr int K_ = 20;
constexpr float SLOPE_ = 0.2f;

typedef __attribute__((ext_vector_type(8))) short bf16x8;
typedef __attribute__((ext_vector_type(4))) float f32x4;

__device__ __forceinline__ float lrelu(float v) { return v > 0.0f ? v : SLOPE_ * v; }

__device__ __forceinline__ void async16(const void* g, void* l) {
  __builtin_amdgcn_global_load_lds((const __attribute__((address_space(1))) unsigned int*)g,
                                   (__attribute__((address_space(3))) unsigned int*)l, 16, 0, 0);
}

__device__ __forceinline__ unsigned long long shflx64(unsigned long long v, int m) {
  return __shfl_xor(v, m, 64);
}

__device__ __forceinline__ unsigned short f2bf(float f) {
  unsigned u = __float_as_uint(f);
  u += 0x7fff + ((u >> 16) & 1);
  return (unsigned short)(u >> 16);
}

// Build Wp[2O x C]: rows [0,O) = Wd = W[:, :C]; rows [O,2O) = Wc - Wd
__global__ void prep_wp(const float* __restrict__ W, float* __restrict__ Wp, int O, int C) {
  int i = blockIdx.x * 256 + threadIdx.x;
  if (i >= 2 * O * C) return;
  int o = i / C, c = i - o * C;
  if (o < O)
    Wp[i] = W[o * 2 * C + c];
  else
    Wp[i] = W[(o - O) * 2 * C + C + c] - W[(o - O) * 2 * C + c];
}

// fp32 -> bf16 (RNE), vectorized x4, contiguous
__global__ void cvt_bf16(const float4* __restrict__ src, ushort4* __restrict__ dst, int n4) {
  int i = blockIdx.x * 256 + threadIdx.x;
  if (i >= n4) return;
  float4 v = src[i];
  ushort4 o = {f2bf(v.x), f2bf(v.y), f2bf(v.z), f2bf(v.w)};
  dst[i] = o;
}

// hcat[:,128:256) fp32 -> bf16 interleaved at hcat ushort-offset row*1024+512
__global__ void cvt_rows_bf16(float* __restrict__ hcat) {
  int i = blockIdx.x * 256 + threadIdx.x;
  if (i >= B_ * N_ * 32) return;
  int row = i >> 5, seg = i & 31;
  float4 v = *(const float4*)(hcat + (size_t)row * 512 + 128 + seg * 4);
  ushort4 o = {f2bf(v.x), f2bf(v.y), f2bf(v.z), f2bf(v.w)};
  *(ushort4*)((unsigned short*)hcat + (size_t)row * 1024 + 512 + seg * 4) = o;
}

// norms of x rows (C=3)
__global__ void norms_x(const float* __restrict__ x, float* __restrict__ xx) {
  int i = blockIdx.x * 256 + threadIdx.x;
  if (i >= B_ * N_) return;
  const float* p = x + (size_t)i * 3;
  xx[i] = p[0] * p[0] + p[1] * p[1] + p[2] * p[2];
}

// Transpose features: hin rows (stride, C cols) -> xT[b][CP][N_], zero-padded.
template <int C, int CP>
__global__ __launch_bounds__(256) void transpose_feat(const float* __restrict__ hin, int stride,
                                                      float* __restrict__ xT) {
  __shared__ float ts[64][CP + 1];
  const int b = blockIdx.x & 7, n0 = (blockIdx.x >> 3) * 64;  // XCD-pinned batch
  for (int i = threadIdx.x; i < 64 * C; i += 256) {
    int n = i / C, c = i - n * C;
    ts[n][c] = hin[(size_t)(b * N_ + n0 + n) * stride + c];
  }
  if (CP > C)
    for (int i = threadIdx.x; i < 64 * (CP - C); i += 256) {
      int n = i / (CP - C), c = C + (i - n * (CP - C));
      ts[n][c] = 0.0f;
    }
  __syncthreads();
  for (int i = threadIdx.x; i < 64 * CP; i += 256) {
    int c = i >> 6, n = i & 63;
    xT[((size_t)b * CP + c) * N_ + n0 + n] = ts[n][c];
  }
}

// kNN (champion config, R17-exact): 8 queries/block, 256 threads, XCD-pinned.
// Direct L2->VGPR candidate loads (two float4/c) with 1-deep register prefetch;
// queries are wave-uniform s_loads. This structure measured 127-132 us for
// C=128 and is the measured plateau of the family (R6/R8/R10/R13/R17/R19 all
// >= it). Exchange: 2 rounds via d2s[8][1024]; wave w owns queries 2w,2w+1:
//   r2[s][i]: m = mb(i)+lp, mb(i) = ((i&15)>>2)*512 + ((i&15)&3)*128 + 4*(i>>4),
//   lp = (lane>>2)*8 + (lane&3).
// Selection: threshold (20th-smallest lane-min via bitonic) + ballot-compact +
// u64 bitonic sort; exact-pop fallback if cnt > 64.
template <int C, int CP>
__global__ __launch_bounds__(256) void knn_kernel(const float* __restrict__ hin, int stride,
                                                  const float* __restrict__ xT,
                                                  const float* __restrict__ xx,
                                                  int* __restrict__ idxo) {
  const int b = blockIdx.x & 7;
  const int q0 = (blockIdx.x >> 3) * 8;
  const int tid = threadIdx.x;
  const int w = tid >> 6, lane = tid & 63;
  const int bN = b * N_;

  __shared__ float d2s[8][1024];
  __shared__ unsigned long long cbuf[4][64];

  const float* qrow0 = hin + (size_t)(bN + q0) * stride;

  float acc[8][8] = {};  // [q][j], m = w*512 + lane*8 + j
  const float* xcol = xT + (size_t)b * CP * N_ + w * 512 + lane * 8;

  float4 p0 = *(const float4*)(xcol);
  float4 p1 = *(const float4*)(xcol + 4);
#pragma unroll 4
  for (int c = 0; c < CP; c++) {
    float4 x0 = p0, x1 = p1;
    if (c + 1 < CP) {
      p0 = *(const float4*)(xcol + (size_t)(c + 1) * N_);
      p1 = *(const float4*)(xcol + (size_t)(c + 1) * N_ + 4);
    }
    float xv[8] = {x0.x, x0.y, x0.z, x0.w, x1.x, x1.y, x1.z, x1.w};
#pragma unroll
    for (int q = 0; q < 8; q++) {
      float qv;
      if constexpr (CP == C)
        qv = qrow0[(size_t)q * stride + c];
      else
        qv = (c < C) ? qrow0[(size_t)q * stride + c] : 0.0f;
#pragma unroll
      for (int j = 0; j < 8; j++) acc[q][j] = fmaf(xv[j], qv, acc[q][j]);
    }
  }

  float4 xm0 = *(const float4*)(xx + bN + w * 512 + lane * 8);
  float4 xm1 = *(const float4*)(xx + bN + w * 512 + lane * 8 + 4);
  float xxm[8] = {xm0.x, xm0.y, xm0.z, xm0.w, xm1.x, xm1.y, xm1.z, xm1.w};
  float qnr[8];
#pragma unroll
  for (int q = 0; q < 8; q++) qnr[q] = xx[bN + q0 + q];
#pragma unroll
  for (int q = 0; q < 8; q++)
#pragma unroll
    for (int j = 0; j < 8; j++)
      acc[q][j] = fmaxf(fmaf(-2.0f, acc[q][j], xxm[j] + qnr[q]), 0.0f);

  float r2[2][32];
#pragma unroll
  for (int jc = 0; jc < 2; jc++) {
    __syncthreads();
#pragma unroll
    for (int q = 0; q < 8; q++) {
      float4 v = {acc[q][jc * 4 + 0], acc[q][jc * 4 + 1], acc[q][jc * 4 + 2],
                  acc[q][jc * 4 + 3]};
      *(float4*)&d2s[q][w * 256 + lane * 4] = v;
    }
    __syncthreads();
#pragma unroll
    for (int s = 0; s < 2; s++)
#pragma unroll
      for (int t = 0; t < 16; t++) r2[s][jc * 16 + t] = d2s[2 * w + s][t * 64 + lane];
  }

  const float INF = __int_as_float(0x7f800000);
  const int lp = (lane >> 2) * 8 + (lane & 3);
  unsigned long long* cb = cbuf[w];

#pragma unroll
  for (int s = 0; s < 2; s++) {
    const int q = 2 * w + s;
    int* outp = idxo + (size_t)(bN + q0 + q) * K_;

    float lmin = r2[s][0];
#pragma unroll
    for (int i = 1; i < 32; i++) lmin = fminf(lmin, r2[s][i]);
    float sv = lmin;
#pragma unroll
    for (int k = 2; k <= 64; k <<= 1)
#pragma unroll
      for (int j = k >> 1; j > 0; j >>= 1) {
        float p = __shfl_xor(sv, j, 64);
        bool takeMax = ((lane & j) != 0) == ((lane & k) == 0);
        sv = takeMax ? fmaxf(sv, p) : fminf(sv, p);
      }
    float T = __shfl(sv, 19, 64);

    unsigned cnt = 0;
#pragma unroll
    for (int i = 0; i < 32; i++) {
      const int t = i & 15;
      const int mb = (t >> 2) * 512 + (t & 3) * 128 + (i >> 4) * 4;
      bool pred = r2[s][i] <= T;
      unsigned long long mk = __ballot(pred);
      if (mk) {
        int off = __popcll(mk & ((1ull << lane) - 1ull));
        unsigned pos = cnt + (unsigned)off;
        if (pred && pos < 64)
          cb[pos] = ((unsigned long long)__float_as_uint(r2[s][i]) << 32) | (unsigned)(mb + lp);
        cnt += (unsigned)__popcll(mk);
      }
    }

    if (cnt <= 64) {
      unsigned long long v = (lane < (int)cnt) ? cb[lane] : ~0ull;
#pragma unroll
      for (int k = 2; k <= 64; k <<= 1)
#pragma unroll
        for (int j = k >> 1; j > 0; j >>= 1) {
          unsigned long long p = shflx64(v, j);
          bool takeMax = ((lane & j) != 0) == ((lane & k) == 0);
          bool lt = v < p;
          v = (takeMax == lt) ? p : v;
        }
      if (lane < K_) outp[lane] = (int)(unsigned)(v & 0xffffffffull);
    } else {
      for (int t2 = 0; t2 < K_; t2++) {
        unsigned long long loc = ~0ull;
#pragma unroll
        for (int i = 0; i < 32; i++) {
          const int t = i & 15;
          const int mb = (t >> 2) * 512 + (t & 3) * 128 + (i >> 4) * 4;
          unsigned long long u =
              ((unsigned long long)__float_as_uint(r2[s][i]) << 32) | (unsigned)(mb + lp);
          loc = u < loc ? u : loc;
        }
#pragma unroll
        for (int off = 32; off > 0; off >>= 1) {
          unsigned long long vv = shflx64(loc, off);
          loc = vv < loc ? vv : loc;
        }
        const int mwin = (int)(unsigned)(loc & 0xffffffffull);
        if (lane == 0) outp[t2] = mwin;
#pragma unroll
        for (int i = 0; i < 32; i++) {
          const int t = i & 15;
          const int mb = (t >> 2) * 512 + (t & 3) * 128 + (i >> 4) * 4;
          if (mb + lp == mwin) r2[s][i] = INF;
        }
      }
    }
  }
}

// P[row, o'] = sum_c h[row, c] * Wp[o', c]; XCD-pinned row tiles.
template <int C, int O2>
__global__ void proj_kernel(const float* __restrict__ hin, int stride,
                            const float* __restrict__ Wp, float* __restrict__ P) {
  const int nt = (blockIdx.x & 7) * N_ + (blockIdx.x >> 3) * 16;  // XCD-pinned
  const int o = blockIdx.y * blockDim.x + threadIdx.x;
  __shared__ float hs[16][C];
  for (int i = threadIdx.x; i < 16 * C; i += blockDim.x) {
    int r = i / C, c = i - r * C;
    hs[r][c] = hin[(size_t)(nt + r) * stride + c];
  }
  __syncthreads();
  float acc[16];
#pragma unroll
  for (int t = 0; t < 16; t++) acc[t] = 0.0f;
  const float* wr = Wp + (size_t)o * C;
  if constexpr (C % 4 == 0) {
    for (int cg = 0; cg < C; cg += 4) {
      float4 w = *(const float4*)(wr + cg);
#pragma unroll
      for (int t = 0; t < 16; t++) {
        float4 h = *(const float4*)(&hs[t][cg]);
        acc[t] += w.x * h.x + w.y * h.y + w.z * h.z + w.w * h.w;
      }
    }
  } else {
    for (int c = 0; c < C; c++) {
      float w = wr[c];
#pragma unroll
      for (int t = 0; t < 16; t++) acc[t] += w * hs[t][c];
    }
  }
#pragma unroll
  for (int t = 0; t < 16; t++) P[(size_t)(nt + t) * O2 + o] = acc[t];
}

// Layer-4 proj via bf16 MFMA (K=128), XCD-pinned m-tiles.
__global__ __launch_bounds__(256) void gemm_proj(const unsigned short* __restrict__ A, int astride,
                                                 const unsigned short* __restrict__ Bw,
                                                 float* __restrict__ P) {
  const int m0 = ((blockIdx.x & 7) * 16 + (blockIdx.x >> 3)) * 128;  // XCD-pinned
  const int n0 = blockIdx.y * 128;
  const int tid = threadIdx.x;
  const int w = tid >> 6, lane = tid & 63;
  const int wm = w & 1, wn = w >> 1;

  __shared__ unsigned short lA[128 * 32];
  __shared__ unsigned short lB[128 * 32];

  const int r0 = (w * 2 + 0) * 16 + (lane >> 2);
  const int r1 = (w * 2 + 1) * 16 + (lane >> 2);
  const int ks = (lane & 3) * 8;
  const unsigned short* a0 = A + (size_t)(m0 + r0) * astride + ks;
  const unsigned short* a1 = A + (size_t)(m0 + r1) * astride + ks;
  const unsigned short* b0 = Bw + (size_t)(n0 + r0) * 128 + ks;
  const unsigned short* b1 = Bw + (size_t)(n0 + r1) * 128 + ks;
  unsigned short* lA0 = lA + (w * 2 + 0) * 512;
  unsigned short* lA1 = lA + (w * 2 + 1) * 512;
  unsigned short* lB0 = lB + (w * 2 + 0) * 512;
  unsigned short* lB1 = lB + (w * 2 + 1) * 512;

  f32x4 acc[4][4] = {};
  const int ka = (lane >> 4) * 8;

  for (int k0 = 0; k0 < 128; k0 += 32) {
    __syncthreads();
    async16(a0 + k0, lA0);
    async16(a1 + k0, lA1);
    async16(b0 + k0, lB0);
    async16(b1 + k0, lB1);
    __syncthreads();
    bf16x8 af[4], bfr[4];
#pragma unroll
    for (int mt = 0; mt < 4; mt++)
      af[mt] = *(const bf16x8*)&lA[(wm * 64 + mt * 16 + (lane & 15)) * 32 + ka];
#pragma unroll
    for (int nt = 0; nt < 4; nt++)
      bfr[nt] = *(const bf16x8*)&lB[(wn * 64 + nt * 16 + (lane & 15)) * 32 + ka];
#pragma unroll
    for (int mt = 0; mt < 4; mt++)
#pragma unroll
      for (int nt = 0; nt < 4; nt++)
        acc[mt][nt] = __builtin_amdgcn_mfma_f32_16x16x32_bf16(af[mt], bfr[nt], acc[mt][nt], 0, 0, 0);
  }

  const int col = n0 + wn * 64 + (lane & 15);
  const int rowb = m0 + wm * 64 + (lane >> 4) * 4;
#pragma unroll
  for (int mt = 0; mt < 4; mt++)
#pragma unroll
    for (int nt = 0; nt < 4; nt++)
#pragma unroll
      for (int r = 0; r < 4; r++)
        P[(size_t)(rowb + mt * 16 + r) * 512 + col + nt * 16] = acc[mt][nt][r];
}

// Combine: 256 threads handle ROWS=256/O rows; XCD-pinned.
template <int O>
__global__ __launch_bounds__(256) void combine_kernel(const float* __restrict__ P,
                                                      const int* __restrict__ idxo,
                                                      const float* __restrict__ bias,
                                                      float* __restrict__ hout,
                                                      float* __restrict__ xxo) {
  constexpr int ROWS = 256 / O;
  const int bb = blockIdx.x & 7;
  const int rt = blockIdx.x >> 3;
  const int r = threadIdx.x / O;
  const int o = threadIdx.x & (O - 1);
  const int row = bb * N_ + rt * ROWS + r;
  __shared__ int idxs[ROWS][K_];
  __shared__ float ps[ROWS][O / 64 > 0 ? O / 64 : 1];
  if (o < K_) idxs[r][o] = idxo[(size_t)row * K_ + o];
  __syncthreads();
  const int base_row = bb * N_;
  float g = -3.4e38f;
#pragma unroll
  for (int k = 0; k < K_; k++) {
    float v = P[(size_t)(base_row + idxs[r][k]) * (2 * O) + o];
    g = fmaxf(g, v);
  }
  float ba = P[(size_t)row * (2 * O) + O + o];
  float val = lrelu(g + ba + bias[o]);
  hout[(size_t)row * 512 + o] = val;
  if (xxo) {
    float sq = val * val;
#pragma unroll
    for (int off = 32; off > 0; off >>= 1) sq += __shfl_xor(sq, off, 64);
    if constexpr (O == 64) {
      if (o == 0) xxo[row] = sq;
    } else {
      if ((threadIdx.x & 63) == 0) ps[r][o >> 6] = sq;
      __syncthreads();
      if (o == 0) {
        float t = ps[r][0];
#pragma unroll
        for (int u = 1; u < O / 64; u++) t += ps[r][u];
        xxo[row] = t;
      }
    }
  }
}

// Final GEMM: 128x128 tile, BK=32, bf16 MFMA, max-over-rows epilogue; XCD-pinned.
__global__ __launch_bounds__(256) void gemm_final(const unsigned short* __restrict__ A,
                                                  const unsigned short* __restrict__ Bw,
                                                  float* __restrict__ part) {
  const int mt5 = (blockIdx.x & 7) * 16 + (blockIdx.x >> 3);
  const int m0 = mt5 * 128;
  const int n0 = blockIdx.y * 128;
  const int tid = threadIdx.x;
  const int w = tid >> 6, lane = tid & 63;
  const int wm = w & 1, wn = w >> 1;

  __shared__ unsigned short lA[128 * 32];
  __shared__ unsigned short lB[128 * 32];
  __shared__ float ldsred[2][128];

  const int r0 = (w * 2 + 0) * 16 + (lane >> 2);
  const int r1 = (w * 2 + 1) * 16 + (lane >> 2);
  const int ks = (lane & 3) * 8;
  const unsigned short* a0 = A + (size_t)(m0 + r0) * 512 + ks;
  const unsigned short* a1 = A + (size_t)(m0 + r1) * 512 + ks;
  const unsigned short* b0 = Bw + (size_t)(n0 + r0) * 512 + ks;
  const unsigned short* b1 = Bw + (size_t)(n0 + r1) * 512 + ks;
  unsigned short* lA0 = lA + (w * 2 + 0) * 512;
  unsigned short* lA1 = lA + (w * 2 + 1) * 512;
  unsigned short* lB0 = lB + (w * 2 + 0) * 512;
  unsigned short* lB1 = lB + (w * 2 + 1) * 512;

  f32x4 acc[4][4] = {};
  const int ka = (lane >> 4) * 8;

  for (int k0 = 0; k0 < 512; k0 += 32) {
    __syncthreads();
    async16(a0 + k0, lA0);
    async16(a1 + k0, lA1);
    async16(b0 + k0, lB0);
    async16(b1 + k0, lB1);
    __syncthreads();
    bf16x8 af[4], bfr[4];
#pragma unroll
    for (int mt = 0; mt < 4; mt++)
      af[mt] = *(const bf16x8*)&lA[(wm * 64 + mt * 16 + (lane & 15)) * 32 + ka];
#pragma unroll
    for (int nt = 0; nt < 4; nt++)
      bfr[nt] = *(const bf16x8*)&lB[(wn * 64 + nt * 16 + (lane & 15)) * 32 + ka];
#pragma unroll
    for (int mt = 0; mt < 4; mt++)
#pragma unroll
      for (int nt = 0; nt < 4; nt++)
        acc[mt][nt] = __builtin_amdgcn_mfma_f32_16x16x32_bf16(af[mt], bfr[nt], acc[mt][nt], 0, 0, 0);
  }

#pragma unroll
  for (int nt = 0; nt < 4; nt++) {
    float v = -3.4e38f;
#pragma unroll
    for (int mt = 0; mt < 4; mt++)
#pragma unroll
      for (int r = 0; r < 4; r++) v = fmaxf(v, acc[mt][nt][r]);
    v = fmaxf(v, __shfl_xor(v, 16, 64));
    v = fmaxf(v, __shfl_xor(v, 32, 64));
    if (lane < 16) ldsred[wm][wn * 64 + nt * 16 + lane] = v;
  }
  __syncthreads();
  if (tid < 128) {
    float v = fmaxf(ldsred[0][tid], ldsred[1][tid]);
    const int b = blockIdx.x & 7, s5 = blockIdx.x >> 3;
    part[(size_t)(b * 16 + s5) * 1024 + n0 + tid] = v;
  }
}

__global__ void final_reduce(const float* __restrict__ part, const float* __restrict__ bf,
                             float* __restrict__ out) {
  int i = blockIdx.x * 256 + threadIdx.x;
  if (i >= B_ * 1024) return;
  int b = i >> 10, o = i & 1023;
  float m = -3.4e38f;
  for (int s = 0; s < 16; s++) m = fmaxf(m, part[(size_t)(b * 16 + s) * 1024 + o]);
  out[i] = lrelu(m + bf[o]);
}

extern "C" void kernel_launch(void* const* d_in, const int* in_sizes, int n_in, void* d_out,
                              int out_size, void* d_ws, size_t ws_size, hipStream_t stream) {
  (void)in_sizes; (void)n_in; (void)out_size; (void)ws_size;
  const float* x = (const float*)d_in[0];
  const float* W1 = (const float*)d_in[1];
  const float* b1 = (const float*)d_in[2];
  const float* W2 = (const float*)d_in[3];
  const float* b2 = (const float*)d_in[4];
  const float* W3 = (const float*)d_in[5];
  const float* b3 = (const float*)d_in[6];
  const float* W4 = (const float*)d_in[7];
  const float* b4 = (const float*)d_in[8];
  const float* Wf = (const float*)d_in[9];
  const float* bf = (const float*)d_in[10];

  float* ws = (float*)d_ws;
  float* hcat = ws;                               // B*N*512 floats (32 MB)
  float* P = hcat + (size_t)B_ * N_ * 512;        // B*N*512 floats (32 MB)
  int* idx = (int*)(P + (size_t)B_ * N_ * 512);   // B*N*20 ints
  float* Wp = (float*)(idx + (size_t)B_ * N_ * K_);
  float* part = Wp + 512 * 128;                   // 8*16*1024 floats
  float* xxb = part + 8 * 16 * 1024;              // B*N floats (row norms)
  float* out = (float*)d_out;
  float* xT = P;                                  // alias P: dead before proj writes P
  unsigned short* hcat_bf = (unsigned short*)P;   // alias P (dead after layer-4)
  unsigned short* Wf_bf = hcat_bf + (size_t)B_ * N_ * 512;
  unsigned short* A4_bf = (unsigned short*)hcat + 512;  // interleaved, stride 1024 ushorts
  unsigned short* Wp_bf = (unsigned short*)part;        // part dead until gemm_final

  dim3 knng(N_ / 8 * B_);
  dim3 trg(N_ / 64 * B_);

  // Layer 1: C=3 -> O=64
  prep_wp<<<(2 * 64 * 3 + 255) / 256, 256, 0, stream>>>(W1, Wp, 64, 3);
  norms_x<<<(B_ * N_ + 255) / 256, 256, 0, stream>>>(x, xxb);
  transpose_feat<3, 4><<<trg, 256, 0, stream>>>(x, 3, xT);
  knn_kernel<3, 4><<<knng, 256, 0, stream>>>(x, 3, xT, xxb, idx);
  proj_kernel<3, 128><<<dim3(B_ * N_ / 16, 1), 128, 0, stream>>>(x, 3, Wp, P);
  combine_kernel<64><<<B_ * N_ / 4, 256, 0, stream>>>(P, idx, b1, hcat + 0, xxb);

  // Layer 2: C=64 -> O=64
  prep_wp<<<(2 * 64 * 64 + 255) / 256, 256, 0, stream>>>(W2, Wp, 64, 64);
  transpose_feat<64, 64><<<trg, 256, 0, stream>>>(hcat + 0, 512, xT);
  knn_kernel<64, 64><<<knng, 256, 0, stream>>>(hcat + 0, 512, xT, xxb, idx);
  proj_kernel<64, 128><<<dim3(B_ * N_ / 16, 1), 128, 0, stream>>>(hcat + 0, 512, Wp, P);
  combine_kernel<64><<<B_ * N_ / 4, 256, 0, stream>>>(P, idx, b2, hcat + 64, xxb);

  // Layer 3: C=64 -> O=128
  prep_wp<<<(2 * 128 * 64 + 255) / 256, 256, 0, stream>>>(W3, Wp, 128, 64);
  transpose_feat<64, 64><<<trg, 256, 0, stream>>>(hcat + 64, 512, xT);
  knn_kernel<64, 64><<<knng, 256, 0, stream>>>(hcat + 64, 512, xT, xxb, idx);
  proj_kernel<64, 256><<<dim3(B_ * N_ / 16, 1), 256, 0, stream>>>(hcat + 64, 512, Wp, P);
  combine_kernel<128><<<B_ * N_ / 2, 256, 0, stream>>>(P, idx, b3, hcat + 128, xxb);

  // Layer 4: C=128 -> O=256; proj via bf16 MFMA
  prep_wp<<<(2 * 256 * 128 + 255) / 256, 256, 0, stream>>>(W4, Wp, 256, 128);
  transpose_feat<128, 128><<<trg, 256, 0, stream>>>(hcat + 128, 512, xT);
  knn_kernel<128, 128><<<knng, 256, 0, stream>>>(hcat + 128, 512, xT, xxb, idx);
  cvt_rows_bf16<<<(B_ * N_ * 32 + 255) / 256, 256, 0, stream>>>(hcat);
  cvt_bf16<<<(512 * 128 / 4 + 255) / 256, 256, 0, stream>>>(
      (const float4*)Wp, (ushort4*)Wp_bf, 512 * 128 / 4);
  gemm_proj<<<dim3(B_ * N_ / 128, 4), 256, 0, stream>>>(A4_bf, 1024, Wp_bf, P);
  combine_kernel<256><<<B_ * N_, 256, 0, stream>>>(P, idx, b4, hcat + 256, nullptr);

  // Final 1x1 conv via bf16 MFMA + fused max-over-rows
  cvt_bf16<<<(B_ * N_ * 512 / 4 + 255) / 256, 256, 0, stream>>>(
      (const float4*)hcat, (ushort4*)hcat_bf, B_ * N_ * 512 / 4);
  cvt_bf16<<<(1024 * 512 / 4 + 255) / 256, 256, 0, stream>>>(
      (const float4*)Wf, (ushort4*)Wf_bf, 1024 * 512 / 4);
  gemm_final<<<dim3(128, 8), 256, 0, stream>>>(hcat_bf, Wf_bf, part);
  final_reduce<<<(B_ * 1024 + 255) / 256, 256, 0, stream>>>(part, bf, out);
}